// Round 6
// baseline (2831.232 us; speedup 1.0000x reference)
//
#include <hip/hip_runtime.h>

#define TT 256
#define BB 32
#define HH 512
#define EE 512
#define GG 2048
#define MM 8192
#define NWG 32   // workgroups in lstm_rec (each owns 16 cols of BOTH directions)

typedef __attribute__((ext_vector_type(8))) short bf16x8;
typedef __attribute__((ext_vector_type(4))) float f32x4;
typedef __attribute__((ext_vector_type(4))) unsigned short us4;
typedef unsigned long long ull;

__device__ inline float b2f(unsigned short u) {
    union { unsigned int i; float f; } v; v.i = ((unsigned int)u) << 16; return v.f;
}
__device__ inline unsigned short f2b(float f) {
    union { float f; unsigned int i; } v; v.f = f;
    unsigned int x = v.i;
    return (unsigned short)((x + 0x7FFFu + ((x >> 16) & 1u)) >> 16);
}
__device__ inline float sigm(float x) { return 1.f / (1.f + __expf(-x)); }
__device__ inline float tanh_f(float x) {
    float ax = fminf(fabsf(x), 12.f);
    float e = __expf(2.f * ax);
    float r = (e - 1.f) / (e + 1.f);
    return x < 0.f ? -r : r;
}

#define AGLD(p) __hip_atomic_load((p), __ATOMIC_RELAXED, __HIP_MEMORY_SCOPE_AGENT)
#define ASTD(p, v) __hip_atomic_store((p), (v), __ATOMIC_RELAXED, __HIP_MEMORY_SCOPE_AGENT)

// ---------------- prep + embed fused ----------------
__global__ void prep_embed_k(const int* __restrict__ ids, const float* __restrict__ emb,
                             const float* __restrict__ wihf, const float* __restrict__ whhf,
                             const float* __restrict__ wihb, const float* __restrict__ whhb,
                             const float* __restrict__ bihf, const float* __restrict__ bhhf,
                             const float* __restrict__ bihb, const float* __restrict__ bhhb,
                             unsigned short* __restrict__ xb, unsigned short* __restrict__ wih,
                             unsigned short* __restrict__ whh, float* __restrict__ bias)
{
    int v = blockIdx.x * 256 + threadIdx.x;   // 0..1048575
    {   // embedding: x[row][col4..col4+3]
        int row = v >> 7;
        int col4 = (v & 127) * 4;
        int id = ids[row];
        float4 e;
        if (id != 0) e = *(const float4*)(emb + (size_t)id * 512 + col4);
        else { e.x = 0.f; e.y = 0.f; e.z = 0.f; e.w = 0.f; }
        us4 o; o.x = f2b(e.x); o.y = f2b(e.y); o.z = f2b(e.z); o.w = f2b(e.w);
        *(us4*)(xb + (size_t)row * 512 + col4) = o;
    }
    if (v < 262144) {   // weight convert + bias sums
        float4 a; us4 o;
        a = ((const float4*)wihf)[v];
        o.x = f2b(a.x); o.y = f2b(a.y); o.z = f2b(a.z); o.w = f2b(a.w);
        *(us4*)(wih + (size_t)v * 4) = o;
        a = ((const float4*)whhf)[v];
        o.x = f2b(a.x); o.y = f2b(a.y); o.z = f2b(a.z); o.w = f2b(a.w);
        *(us4*)(whh + (size_t)v * 4) = o;
        a = ((const float4*)wihb)[v];
        o.x = f2b(a.x); o.y = f2b(a.y); o.z = f2b(a.z); o.w = f2b(a.w);
        *(us4*)(wih + 1048576 + (size_t)v * 4) = o;
        a = ((const float4*)whhb)[v];
        o.x = f2b(a.x); o.y = f2b(a.y); o.z = f2b(a.z); o.w = f2b(a.w);
        *(us4*)(whh + 1048576 + (size_t)v * 4) = o;
        if (v < 2048)      bias[v] = bihf[v] + bhhf[v];
        else if (v < 4096) bias[v] = bihb[v - 2048] + bhhb[v - 2048];
    }
}

// ---------------- persistent bidirectional LSTM, dual-direction ping-pong ----------------
// grid 32: wg owns hidden cols [wg*16, wg*16+16) of BOTH directions. 1 WG/CU.
// Each step t runs phase A (forward, te=t) then phase B (backward, te=255-t).
// Direction X's exchange (store+drain+flag / poll / gather) is overlapped with
// direction Y's compute phase: poll loads issued right after flag-set fly during
// the opposite phase; the gather is issued mid-opposite-phase AFTER the flag is
// observed (correct load ordering) and lands under the opposite phase's tail.
// Per combined step: 4 barriers, 2 drains — covers BOTH directions.
__global__ __launch_bounds__(256, 1) void lstm_rec(const unsigned short* __restrict__ whh,
                                                   const unsigned short* __restrict__ wih,
                                                   const unsigned short* __restrict__ xb,
                                                   const float* __restrict__ bias,
                                                   unsigned short* __restrict__ h_all,
                                                   unsigned int* __restrict__ cnt)
{
    __shared__ unsigned short xbufA[32][520];     // x_te(A) staging
    __shared__ unsigned short xbufB[32][520];     // x_te(B) staging
    __shared__ unsigned short hbuf[32][520];      // h_{t-1} staging (phase-alternating)
    __shared__ float gbuf[4][32][16];             // gate pre-activations

    const int wg = blockIdx.x;                    // 0..31
    const int js = wg * 16;
    const int tid = threadIdx.x;
    const int wave = tid >> 6, lane = tid & 63;
    const int quad = lane >> 4, r16 = lane & 15;
    const int colw = wave * 512 + js + r16;       // gate-row within a direction

    // B-fragments for both directions in registers (4 x 64 VGPR)
    bf16x8 wfrA[16], xfrA[16], wfrB[16], xfrB[16];
    {
        const unsigned short* wrA = whh + (size_t)colw * 512;
        const unsigned short* xrA = wih + (size_t)colw * 512;
        const unsigned short* wrB = whh + (size_t)GG * HH + (size_t)colw * 512;
        const unsigned short* xrB = wih + (size_t)GG * EE + (size_t)colw * 512;
#pragma unroll
        for (int kc = 0; kc < 16; ++kc) {
            wfrA[kc] = *(const bf16x8*)(wrA + kc * 32 + quad * 8);
            xfrA[kc] = *(const bf16x8*)(xrA + kc * 32 + quad * 8);
            wfrB[kc] = *(const bf16x8*)(wrB + kc * 32 + quad * 8);
            xfrB[kc] = *(const bf16x8*)(xrB + kc * 32 + quad * 8);
        }
    }
    const float bswA = bias[colw];
    const float bswB = bias[GG + colw];

    // cell states: thread owns (b = tid>>3, j = js + 2*(tid&7) + {0,1}) per direction
    const int cb = tid >> 3, cj = (tid & 7) * 2;
    float cA0 = 0.f, cA1 = 0.f, cB0 = 0.f, cB1 = 0.f;

    unsigned short* hdA = h_all;                              // [te][b][512]
    unsigned short* hdB = h_all + (size_t)TT * BB * HH;
    unsigned int* flgA = cnt;
    unsigned int* flgB = cnt + NWG;
    const ull* xbsrc = (const ull*)xb;                        // 128 ull per 512-col row

    // prologue: stage x for t=0 of both directions
#pragma unroll
    for (int i = 0; i < 16; ++i) {
        int v = tid + i * 256;
        int row = v >> 7, wi = v & 127;
        *(ull*)&xbufA[row][wi * 4] = xbsrc[((size_t)(row << 8) + 0) * 128 + wi];
        *(ull*)&xbufB[row][wi * 4] = xbsrc[((size_t)(row << 8) + (TT - 1)) * 128 + wi];
    }
    __syncthreads();

    ull hvA[16], hvB[16], xpreA[16], xpreB[16];
    unsigned int pfA = 0, pfB = 0;

    for (int t = 0; t < TT; ++t) {
        const int te2 = TT - 1 - t;

        // ================= PHASE A (forward, te = t) =================
        if (t > 0) {
#pragma unroll
            for (int i = 0; i < 16; ++i) {
                int v = tid + i * 256;
                int row = v >> 7, wi = v & 127;
                *(ull*)&hbuf[row][wi * 4]  = hvA[i];    // h_A(t-1), gathered mid-B(t-1)
                *(ull*)&xbufB[row][wi * 4] = xpreB[i];  // x for te_B(t), loaded in B(t-1)
            }
        }
        __syncthreads();   // B1_A

        // issue x prefetch for te_A(t+1)
        if (t + 1 < TT) {
#pragma unroll
            for (int i = 0; i < 16; ++i) {
                int v = tid + i * 256;
                int row = v >> 7, wi = v & 127;
                xpreA[i] = xbsrc[((size_t)(row << 8) + (t + 1)) * 128 + wi];
            }
        }

        f32x4 alo = {0.f, 0.f, 0.f, 0.f}, ahi = {0.f, 0.f, 0.f, 0.f};
        if (t > 0) {   // h-MFMA_A
#pragma unroll
            for (int kc = 0; kc < 16; ++kc) {
                const int ko = kc * 32 + quad * 8;
                bf16x8 aflo = *(const bf16x8*)&hbuf[r16][ko];
                bf16x8 afhi = *(const bf16x8*)&hbuf[16 + r16][ko];
                alo = __builtin_amdgcn_mfma_f32_16x16x32_bf16(aflo, wfrA[kc], alo, 0, 0, 0);
                ahi = __builtin_amdgcn_mfma_f32_16x16x32_bf16(afhi, wfrA[kc], ahi, 0, 0, 0);
            }
        }

        // E3_A: confirm flag_B >= t (set one phase ago), then gather h_B(t-1) @ te 256-t
        if (t > 0) {
            unsigned int f = pfB;
            const unsigned int tgt = (unsigned int)t;
            while (__ballot(f >= tgt) != ~0ull)
                f = AGLD(&flgB[lane & 31]);
            asm volatile("" ::: "memory");   // no hoist of gather above flag confirm
            const ull* hs = (const ull*)(hdB + (size_t)(TT - t) * BB * HH);
#pragma unroll
            for (int i = 0; i < 16; ++i)
                hvB[i] = AGLD(&hs[tid + i * 256]);
        }

        // x-MFMA_A (gather_B flies underneath)
#pragma unroll
        for (int kc = 0; kc < 16; ++kc) {
            const int ko = kc * 32 + quad * 8;
            bf16x8 aflo = *(const bf16x8*)&xbufA[r16][ko];
            bf16x8 afhi = *(const bf16x8*)&xbufA[16 + r16][ko];
            alo = __builtin_amdgcn_mfma_f32_16x16x32_bf16(aflo, xfrA[kc], alo, 0, 0, 0);
            ahi = __builtin_amdgcn_mfma_f32_16x16x32_bf16(afhi, xfrA[kc], ahi, 0, 0, 0);
        }

#pragma unroll
        for (int r = 0; r < 4; ++r) {
            gbuf[wave][quad * 4 + r][r16]      = alo[r] + bswA;
            gbuf[wave][16 + quad * 4 + r][r16] = ahi[r] + bswA;
        }
        __syncthreads();   // B2_A

        {   // nonlinearity A + h store
            float2 iv = *(const float2*)&gbuf[0][cb][cj];
            float2 fv = *(const float2*)&gbuf[1][cb][cj];
            float2 gv = *(const float2*)&gbuf[2][cb][cj];
            float2 ov = *(const float2*)&gbuf[3][cb][cj];
            cA0 = sigm(fv.x) * cA0 + sigm(iv.x) * tanh_f(gv.x);
            cA1 = sigm(fv.y) * cA1 + sigm(iv.y) * tanh_f(gv.y);
            float h0 = sigm(ov.x) * tanh_f(cA0);
            float h1 = sigm(ov.y) * tanh_f(cA1);
            unsigned int packed = (unsigned int)f2b(h0) | ((unsigned int)f2b(h1) << 16);
            unsigned int* hp = (unsigned int*)(hdA + (size_t)t * BB * HH + cb * 512 + js + cj);
            __hip_atomic_store(hp, packed, __ATOMIC_RELAXED, __HIP_MEMORY_SCOPE_AGENT);
        }
        asm volatile("s_waitcnt vmcnt(0)" ::: "memory");   // release: data visible before flag
        if (tid == 0) ASTD(&flgA[wg], (unsigned int)(t + 1));
        if (t + 1 < TT) pfA = AGLD(&flgA[lane & 31]);      // poll for E3_B, flies during rest of A/B

        // ================= PHASE B (backward, te = te2) =================
#pragma unroll
        for (int i = 0; i < 16; ++i) {
            int v = tid + i * 256;
            int row = v >> 7, wi = v & 127;
            if (t > 0)      *(ull*)&hbuf[row][wi * 4]  = hvB[i];   // h_B(t-1)
            if (t + 1 < TT) *(ull*)&xbufA[row][wi * 4] = xpreA[i]; // x for te_A(t+1)
        }
        __syncthreads();   // B1_B

        // issue x prefetch for te_B(t+1) = te2-1
        if (t + 1 < TT) {
#pragma unroll
            for (int i = 0; i < 16; ++i) {
                int v = tid + i * 256;
                int row = v >> 7, wi = v & 127;
                xpreB[i] = xbsrc[((size_t)(row << 8) + (te2 - 1)) * 128 + wi];
            }
        }

        alo = f32x4{0.f, 0.f, 0.f, 0.f}; ahi = f32x4{0.f, 0.f, 0.f, 0.f};
        if (t > 0) {   // h-MFMA_B
#pragma unroll
            for (int kc = 0; kc < 16; ++kc) {
                const int ko = kc * 32 + quad * 8;
                bf16x8 aflo = *(const bf16x8*)&hbuf[r16][ko];
                bf16x8 afhi = *(const bf16x8*)&hbuf[16 + r16][ko];
                alo = __builtin_amdgcn_mfma_f32_16x16x32_bf16(aflo, wfrB[kc], alo, 0, 0, 0);
                ahi = __builtin_amdgcn_mfma_f32_16x16x32_bf16(afhi, wfrB[kc], ahi, 0, 0, 0);
            }
        }

        // E3_B: confirm flag_A >= t+1 (just set this step), then gather h_A(t)
        if (t + 1 < TT) {
            unsigned int f = pfA;
            const unsigned int tgt = (unsigned int)(t + 1);
            while (__ballot(f >= tgt) != ~0ull)
                f = AGLD(&flgA[lane & 31]);
            asm volatile("" ::: "memory");
            const ull* hs = (const ull*)(hdA + (size_t)t * BB * HH);
#pragma unroll
            for (int i = 0; i < 16; ++i)
                hvA[i] = AGLD(&hs[tid + i * 256]);
        }

        // x-MFMA_B (gather_A flies underneath)
#pragma unroll
        for (int kc = 0; kc < 16; ++kc) {
            const int ko = kc * 32 + quad * 8;
            bf16x8 aflo = *(const bf16x8*)&xbufB[r16][ko];
            bf16x8 afhi = *(const bf16x8*)&xbufB[16 + r16][ko];
            alo = __builtin_amdgcn_mfma_f32_16x16x32_bf16(aflo, xfrB[kc], alo, 0, 0, 0);
            ahi = __builtin_amdgcn_mfma_f32_16x16x32_bf16(afhi, xfrB[kc], ahi, 0, 0, 0);
        }

#pragma unroll
        for (int r = 0; r < 4; ++r) {
            gbuf[wave][quad * 4 + r][r16]      = alo[r] + bswB;
            gbuf[wave][16 + quad * 4 + r][r16] = ahi[r] + bswB;
        }
        __syncthreads();   // B2_B

        {   // nonlinearity B + h store
            float2 iv = *(const float2*)&gbuf[0][cb][cj];
            float2 fv = *(const float2*)&gbuf[1][cb][cj];
            float2 gv = *(const float2*)&gbuf[2][cb][cj];
            float2 ov = *(const float2*)&gbuf[3][cb][cj];
            cB0 = sigm(fv.x) * cB0 + sigm(iv.x) * tanh_f(gv.x);
            cB1 = sigm(fv.y) * cB1 + sigm(iv.y) * tanh_f(gv.y);
            float h0 = sigm(ov.x) * tanh_f(cB0);
            float h1 = sigm(ov.y) * tanh_f(cB1);
            unsigned int packed = (unsigned int)f2b(h0) | ((unsigned int)f2b(h1) << 16);
            unsigned int* hp = (unsigned int*)(hdB + (size_t)te2 * BB * HH + cb * 512 + js + cj);
            __hip_atomic_store(hp, packed, __ATOMIC_RELAXED, __HIP_MEMORY_SCOPE_AGENT);
        }
        asm volatile("s_waitcnt vmcnt(0)" ::: "memory");
        if (tid == 0) ASTD(&flgB[wg], (unsigned int)(t + 1));
        if (t + 1 < TT) pfB = AGLD(&flgB[lane & 31]);      // poll for E3_A(t+1)
    }
}

// ---------------- classifier: logits = [hf|hb] @ cls_w^T + cls_b ----------------
__global__ __launch_bounds__(256) void logits_k(const unsigned short* __restrict__ h_all,
                                                const float* __restrict__ clsw,
                                                const float* __restrict__ clsb,
                                                float* __restrict__ logits)
{
    const int tid = threadIdx.x;
    const int wave = tid >> 6, lane = tid & 63;
    const int wgid = blockIdx.x * 4 + wave;    // 0..1023

    unsigned int wreg[9][8];
#pragma unroll
    for (int c = 0; c < 9; ++c)
#pragma unroll
        for (int q = 0; q < 8; ++q) {
            float w0 = clsw[c * 1024 + (2 * q) * 64 + lane];
            float w1 = clsw[c * 1024 + (2 * q + 1) * 64 + lane];
            wreg[c][q] = (unsigned int)f2b(w0) | ((unsigned int)f2b(w1) << 16);
        }

    const unsigned short* hfb = h_all;
    const unsigned short* hbb = h_all + (size_t)TT * BB * HH;

    for (int i = 0; i < 8; ++i) {
        int m = wgid * 8 + i;                  // m = b*256 + t
        int b = m >> 8, t = m & 255;
        const unsigned short* hf = hfb + ((size_t)t * BB + b) * HH;
        const unsigned short* hb = hbb + ((size_t)t * BB + b) * HH;
        float acc[9];
#pragma unroll
        for (int c = 0; c < 9; ++c) acc[c] = 0.f;
#pragma unroll
        for (int u = 0; u < 16; ++u) {
            const unsigned short* src = (u < 8) ? (hf + u * 64) : (hb + (u - 8) * 64);
            float hv = b2f(src[lane]);
#pragma unroll
            for (int c = 0; c < 9; ++c) {
                unsigned short wv = (u & 1) ? (unsigned short)(wreg[c][u >> 1] >> 16)
                                            : (unsigned short)(wreg[c][u >> 1] & 0xFFFFu);
                acc[c] += hv * b2f(wv);
            }
        }
#pragma unroll
        for (int c = 0; c < 9; ++c) {
            float s = acc[c];
            for (int off = 32; off > 0; off >>= 1) s += __shfl_down(s, off);
            if (lane == 0) logits[(size_t)m * 9 + c] = s + clsb[c];
        }
    }
}

// ---------------- CRF log-likelihood per sequence ----------------
__global__ void crf_k(const float* __restrict__ logits, const int* __restrict__ label,
                      const float* __restrict__ startp, const float* __restrict__ endp,
                      const float* __restrict__ trans, float* __restrict__ llh)
{
    const int b = blockIdx.x;
    const int lane = threadIdx.x;   // 64
    __shared__ float tr[81];
    __shared__ float alpha[9];
    __shared__ int tags[TT];
    for (int v = lane; v < 81; v += 64) tr[v] = trans[v];
    for (int v = lane; v < TT; v += 64) tags[v] = label[b * TT + v];
    __syncthreads();
    const float* lg = logits + (size_t)b * TT * 9;

    float part = 0.f; int mcnt = 0;
    for (int t = lane; t < TT; t += 64) {
        int tg = tags[t];
        bool m = tg > -1;
        if (m) mcnt++;
        if (t == 0)      part += startp[tg] + lg[tg];
        else if (m)      part += lg[t * 9 + tg] + tr[tags[t - 1] * 9 + tg];
    }
    for (int off = 32; off > 0; off >>= 1) {
        part += __shfl_down(part, off);
        mcnt += __shfl_down(mcnt, off);
    }
    part = __shfl(part, 0);
    mcnt = __shfl(mcnt, 0);
    float num = part + endp[tags[mcnt - 1]];

    if (lane < 9) alpha[lane] = startp[lane] + lg[lane];
    __syncthreads();
    for (int t = 1; t < TT; ++t) {
        float nxt = 0.f;
        if (lane < 9) {
            float mx = -1e30f;
#pragma unroll
            for (int c1 = 0; c1 < 9; ++c1) mx = fmaxf(mx, alpha[c1] + tr[c1 * 9 + lane]);
            float s = 0.f;
#pragma unroll
            for (int c1 = 0; c1 < 9; ++c1) s += __expf(alpha[c1] + tr[c1 * 9 + lane] - mx);
            nxt = mx + __logf(s) + lg[t * 9 + lane];
            if (tags[t] <= -1) nxt = alpha[lane];
        }
        __syncthreads();
        if (lane < 9) alpha[lane] = nxt;
        __syncthreads();
    }
    if (lane == 0) {
        float mx = -1e30f;
#pragma unroll
        for (int c = 0; c < 9; ++c) mx = fmaxf(mx, alpha[c] + endp[c]);
        float s = 0.f;
#pragma unroll
        for (int c = 0; c < 9; ++c) s += __expf(alpha[c] + endp[c] - mx);
        llh[b] = num - (mx + __logf(s));
    }
}

__global__ void fin_k(const float* __restrict__ llh, float* __restrict__ out)
{
    int lane = threadIdx.x;
    float v = (lane < 32) ? llh[lane] : 0.f;
    for (int off = 32; off > 0; off >>= 1) v += __shfl_down(v, off);
    if (lane == 0) out[0] = -v * (1.f / 32.f);
}

// ---------------- launch ----------------
extern "C" void kernel_launch(void* const* d_in, const int* in_sizes, int n_in,
                              void* d_out, int out_size, void* d_ws, size_t ws_size,
                              hipStream_t stream)
{
    const int*   ids   = (const int*)  d_in[0];
    const int*   label = (const int*)  d_in[1];
    const float* emb   = (const float*)d_in[2];
    const float* wihf  = (const float*)d_in[3];
    const float* whhf  = (const float*)d_in[4];
    const float* bihf  = (const float*)d_in[5];
    const float* bhhf  = (const float*)d_in[6];
    const float* wihb  = (const float*)d_in[7];
    const float* whhb  = (const float*)d_in[8];
    const float* bihb  = (const float*)d_in[9];
    const float* bhhb  = (const float*)d_in[10];
    const float* clsw  = (const float*)d_in[11];
    const float* clsb  = (const float*)d_in[12];
    const float* stp   = (const float*)d_in[13];
    const float* enp   = (const float*)d_in[14];
    const float* trp   = (const float*)d_in[15];

    char* ws = (char*)d_ws;
    unsigned short* xb   = (unsigned short*)(ws + 0);           //  8 MB  [8192][512] bf16
    unsigned short* wih  = (unsigned short*)(ws + 8388608);     //  4 MB  [2][2048][512]
    unsigned short* whh  = (unsigned short*)(ws + 12582912);    //  4 MB  [2][2048][512]
    float*          bias = (float*)(ws + 16777216);             // 16 KB  [2][2048]
    unsigned short* hall = (unsigned short*)(ws + 16793600);    // 16 MB  [2][256][32][512]
    float*          lgt  = (float*)(ws + 33570816);             // 288 KB [8192][9]
    float*          llh  = (float*)(ws + 33865728);             // 128 B
    unsigned int*   cnt  = (unsigned int*)(ws + 33865856);      // flags [2][32]

    hipMemsetAsync(cnt, 0, 256, stream);
    prep_embed_k<<<4096, 256, 0, stream>>>(ids, emb, wihf, whhf, wihb, whhb,
                                           bihf, bhhf, bihb, bhhb, xb, wih, whh, bias);
    lstm_rec<<<32, 256, 0, stream>>>(whh, wih, xb, bias, hall, cnt);
    logits_k<<<256, 256, 0, stream>>>(hall, clsw, clsb, lgt);
    crf_k<<<32, 64, 0, stream>>>(lgt, label, stp, enp, trp, llh);
    fin_k<<<1, 64, 0, stream>>>(llh, (float*)d_out);
}